// Round 12
// baseline (167.880 us; speedup 1.0000x reference)
//
#include <hip/hip_runtime.h>
#include <hip/hip_bf16.h>
#include <math.h>

// Problem constants
#define RM 13056         // 256*17*3 rows of flat x
#define KD 512           // feature dim
#define NE 2048          // codebook entries
#define NELEM 6684672.0  // 256*51*512 elements for the mean

// dist kernel tiling
#define BM 128
#define BN 128
#define BK 32            // chunk-layout K-tile (fixed by prep layout)
#define NKT (KD / BK)    // 16 k-tiles
#define NBLK (NE / BN)   // 16 n-blocks
#define NCAND (NBLK * 4) // 64 candidates/row
#define NTAIL (RM / 4)   // 3264 (fallback-path grid)
#define NTAIL2 (RM / 8)  // 1632 (fused-path grid: 2 rows/wave)
#define NREF 5           // max fp64-refined candidates (adaptive, usually 3)
#define RMARGIN 2.0f     // bf16 dist-error margin (~28 sigma; sigma ~0.07)
#define GRID_D ((RM / BM) * NBLK)   // 1632 = 8 * 204
#define XCD_CHUNK (GRID_D / 8)      // 204

typedef __attribute__((ext_vector_type(8))) short bf16x8;
typedef __attribute__((ext_vector_type(4))) float f32x4;
typedef unsigned long long ull;

// async global->LDS, 16B per lane; lds base wave-uniform, HW appends lane*16 (m104)
__device__ __forceinline__ void dma16(const void* g, void* l) {
  __builtin_amdgcn_global_load_lds((const __attribute__((address_space(1))) void*)g,
                                   (__attribute__((address_space(3))) void*)l, 16, 0, 0);
}

// order-preserving (dist, idx) -> u64 key: ascending u64 == lexicographic (d, ix)
__device__ __forceinline__ ull packdi(float d, int ix) {
  unsigned u = __float_as_uint(d);
  u ^= (unsigned)((int)u >> 31) | 0x80000000u;
  return ((ull)u << 32) | (unsigned)ix;
}

// inverse of packdi's float transform (key high word -> original float)
__device__ __forceinline__ float unpackd(ull key) {
  unsigned u = (unsigned)(key >> 32);
  u = (u & 0x80000000u) ? (u ^ 0x80000000u) : ~u;
  return __uint_as_float(u);
}

// ---------------------------------------------------------------------------
// K_prep: fused preprocessing. Single-bf16 candidate path: only hi parts.
#define XB (RM * 64 / 256)   // 3264
#define EB (NE * 64 / 256)   // 512
#define NB (NE / 4)          // 512
__device__ __forceinline__ void split_chunks(const float* __restrict__ src,
                                             unsigned short* __restrict__ hi,
                                             int rows, int o) {
  int t4 = o >> 2;
  int kt = t4 / rows;
  int row = t4 - kt * rows;
  int slot = o & 3;
  int q = slot ^ ((row >> 1) & 3);
  const float* s = src + (size_t)row * KD + kt * 32 + q * 8;
  float4 v0 = ((const float4*)s)[0];
  float4 v1 = ((const float4*)s)[1];
  float f[8] = {v0.x, v0.y, v0.z, v0.w, v1.x, v1.y, v1.z, v1.w};
  unsigned hh[4];
#pragma unroll
  for (int j = 0; j < 4; ++j) {
    __hip_bfloat16 b0 = __float2bfloat16(f[2 * j]);
    __hip_bfloat16 b1 = __float2bfloat16(f[2 * j + 1]);
    hh[j] = (unsigned)*(unsigned short*)&b0 | ((unsigned)*(unsigned short*)&b1 << 16);
  }
  ((uint4*)hi)[o] = make_uint4(hh[0], hh[1], hh[2], hh[3]);
}

__global__ __launch_bounds__(256) void k_prep(const float* __restrict__ X,
                                              const float* __restrict__ E,
                                              unsigned short* __restrict__ Xh,
                                              unsigned short* __restrict__ Eh,
                                              float* __restrict__ EN) {
  const int b = blockIdx.x, tid = threadIdx.x;
  if (b < XB) {
    split_chunks(X, Xh, RM, b * 256 + tid);
  } else if (b < XB + EB) {
    split_chunks(E, Eh, NE, (b - XB) * 256 + tid);
  } else {
    int n = (b - XB - EB) * 4 + (tid >> 6);
    int lane = tid & 63;
    const float* e = E + (size_t)n * KD;
    float s = 0.f;
#pragma unroll
    for (int j = 0; j < 8; ++j) { float v = e[lane + 64 * j]; s += v * v; }
#pragma unroll
    for (int off = 32; off; off >>= 1) s += __shfl_down(s, off);
    if (lane == 0) EN[n] = s;
  }
}

// ---------------------------------------------------------------------------
// LDS chunk addressing (ushort elem offset): chunk q of local row at slot
// q ^ ((row>>1)&3). Conflicts measured 0.
__device__ __forceinline__ int chidx(int row, int q) {
  return (row * 4 + (q ^ ((row >> 1) & 3))) * 8;
}

// K1: single-bf16 MFMA distance tile, BM=128 x BN=128 per block.
// Round-9/10 measured-best: saddr-form staging (r8's VGPR pointer hoisting
// cost 60->80 us -- do not hoist) + XCD-chunked bijective swizzle
// (r10: FETCH 54.4 -> 15.5 MB, the compulsory ideal).
__global__ __launch_bounds__(256, 4) void k_dist_bf16(
    const unsigned short* __restrict__ Xh,
    const unsigned short* __restrict__ Eh,
    const float* __restrict__ EN, ull* __restrict__ cand) {
  __shared__ __align__(16) unsigned short sXh[2][BM * BK];  // 2 x 8 KB
  __shared__ __align__(16) unsigned short sEh[2][BN * BK];  // 2 x 8 KB
  __shared__ float sEN[BN];

  const int tid = threadIdx.x;
  const int lane = tid & 63;
  const int w = tid >> 6;
  const int quad = lane >> 4;
  const int lx = lane & 15;
  const int nbid = (blockIdx.x & 7) * XCD_CHUNK + (blockIdx.x >> 3);
  const int by = nbid & (NBLK - 1);
  const int bx = nbid >> 4;
  const int rowBase = bx * BM;
  const int colBase = by * BN;

  if (tid < BN) sEN[tid] = EN[colBase + tid];

  // frag LDS offsets (constant per lane)
  int aidx[2], bidx[8];
#pragma unroll
  for (int mt = 0; mt < 2; ++mt) aidx[mt] = chidx(w * 32 + mt * 16 + lx, quad);
#pragma unroll
  for (int ct = 0; ct < 8; ++ct) bidx[ct] = chidx(ct * 16 + lx, quad);

  f32x4 acc[2][8];
#pragma unroll
  for (int mt = 0; mt < 2; ++mt)
#pragma unroll
    for (int ct = 0; ct < 8; ++ct) acc[mt][ct] = (f32x4){0.f, 0.f, 0.f, 0.f};

  // stage one 32-K tile (16 KB) into half-buffer h: 4 dma16/thread
  auto stage = [&](int h, int kt) {
    const size_t xbase = ((size_t)kt * RM + rowBase) * 4;   // chunk units
    const size_t ebase = ((size_t)kt * NE + colBase) * 4;
#pragma unroll
    for (int i = 0; i < 2; ++i) {   // X: 512 chunks, E: 512 chunks
      const int c = i * 256 + tid;
      const int ldsOff = (i * 256 + w * 64) * 8;
      dma16(Xh + (xbase + c) * 8, &sXh[h][ldsOff]);
      dma16(Eh + (ebase + c) * 8, &sEh[h][ldsOff]);
    }
  };

  // compute one 32-K tile from half-buffer h: 10 ds_read_b128 + 16 MFMA / wave
  auto compute = [&](int h) {
    bf16x8 Ah[2];
#pragma unroll
    for (int mt = 0; mt < 2; ++mt) Ah[mt] = *(const bf16x8*)&sXh[h][aidx[mt]];
#pragma unroll
    for (int ct = 0; ct < 8; ++ct) {
      bf16x8 Bh = *(const bf16x8*)&sEh[h][bidx[ct]];
#pragma unroll
      for (int mt = 0; mt < 2; ++mt)
        acc[mt][ct] = __builtin_amdgcn_mfma_f32_16x16x32_bf16(Ah[mt], Bh, acc[mt][ct], 0, 0, 0);
    }
  };

#pragma unroll 1
  for (int kt2 = 0; kt2 < NKT / 2; ++kt2) {
    __syncthreads();  // previous iteration's readers done
    stage(0, kt2 * 2);
    stage(1, kt2 * 2 + 1);
    __syncthreads();  // compiler drains vmcnt before barrier
    compute(0);
    compute(1);
  }

  // epilogue: C/D layout col=lane&15, row=quad*4+reg (m89/m91)
  float en[8];
#pragma unroll
  for (int ct = 0; ct < 8; ++ct) en[ct] = sEN[ct * 16 + lx];

#pragma unroll
  for (int mt = 0; mt < 2; ++mt) {
#pragma unroll
    for (int j = 0; j < 4; ++j) {
      float a0 = 3.4e38f, a1 = 3.4e38f, a2 = 3.4e38f, a3 = 3.4e38f;
      int i0 = 0x7fffffff, i1 = i0, i2 = i0, i3 = i0;
#pragma unroll
      for (int ct = 0; ct < 8; ++ct) {
        float d = en[ct] - 2.0f * acc[mt][ct][j];
        int ix = colBase + ct * 16 + lx;
        // ascending idx + strict < keeps the lower index on ties
        if (d < a3) {
          if (d < a2) { a3 = a2; i3 = i2;
            if (d < a1) { a2 = a1; i2 = i1;
              if (d < a0) { a1 = a0; i1 = i0; a0 = d; i0 = ix; }
              else { a1 = d; i1 = ix; } }
            else { a2 = d; i2 = ix; } }
          else { a3 = d; i3 = ix; }
        }
      }
      // 4-round min-extraction across the 16-lane group (keys unique per row)
      ull k0 = packdi(a0, i0), k1 = packdi(a1, i1);
      ull k2 = packdi(a2, i2), k3 = packdi(a3, i3);
      int pos = 0;
      ull res[4];
#pragma unroll
      for (int r = 0; r < 4; ++r) {
        ull h = pos == 0 ? k0 : pos == 1 ? k1 : pos == 2 ? k2 : pos == 3 ? k3 : ~0ull;
        ull m = h;
#pragma unroll
        for (int step = 1; step < 16; step <<= 1) {
          ull o = __shfl_xor(m, step, 16);
          m = o < m ? o : m;
        }
        res[r] = m;
        pos += (h == m) ? 1 : 0;
      }
      if (lx == 0) {
        int row = rowBase + w * 32 + mt * 16 + quad * 4 + j;
        ull* dst = cand + (size_t)row * NCAND + by * 4;
        dst[0] = res[0]; dst[1] = res[1]; dst[2] = res[2]; dst[3] = res[3];
      }
    }
  }
}

// ---------------------------------------------------------------------------
// Single-row fp64 refine (fallback path). WAVE-LOCAL: no block coupling.
__device__ __forceinline__ void refine_core(const float* __restrict__ X,
                                            const float* __restrict__ E,
                                            const int* ci, int nref, int row,
                                            float* __restrict__ outF,
                                            double* __restrict__ part) {
  const int lane = threadIdx.x & 63;
  const float* xr = X + (size_t)row * KD;
  float4 x0 = *(const float4*)(xr + lane * 8);
  float4 x1 = *(const float4*)(xr + lane * 8 + 4);
  double a[NREF];
#pragma unroll
  for (int c = 0; c < NREF; ++c) {
    if (c >= nref) { a[c] = 1.0e300; continue; }   // wave-uniform skip
    const float* er = E + (size_t)ci[c] * KD;
    float4 e0 = *(const float4*)(er + lane * 8);
    float4 e1 = *(const float4*)(er + lane * 8 + 4);
    double s = 0.0;
    double d0 = (double)e0.x - (double)x0.x; s += d0 * d0;
    double d1 = (double)e0.y - (double)x0.y; s += d1 * d1;
    double d2 = (double)e0.z - (double)x0.z; s += d2 * d2;
    double d3 = (double)e0.w - (double)x0.w; s += d3 * d3;
    double d4 = (double)e1.x - (double)x1.x; s += d4 * d4;
    double d5 = (double)e1.y - (double)x1.y; s += d5 * d5;
    double d6 = (double)e1.z - (double)x1.z; s += d6 * d6;
    double d7 = (double)e1.w - (double)x1.w; s += d7 * d7;
    a[c] = s;
  }
#pragma unroll
  for (int c = 0; c < NREF; ++c) {
    if (c >= nref) continue;
#pragma unroll
    for (int off = 32; off; off >>= 1) a[c] += __shfl_down(a[c], off);
  }
  int best = 0;
  if (lane == 0) {
    double d[NREF]; int id[NREF];
#pragma unroll
    for (int c = 0; c < NREF; ++c) { d[c] = a[c]; id[c] = ci[c]; }
    for (int i = 0; i < NREF; ++i)
      for (int j = i + 1; j < NREF; ++j)
        if (d[j] < d[i] || (d[j] == d[i] && id[j] < id[i])) {
          double dt = d[i]; d[i] = d[j]; d[j] = dt;
          int it = id[i]; id[i] = id[j]; id[j] = it;
        }
    part[(size_t)row * 2] = d[0];       // SSE to nearest
    part[(size_t)row * 2 + 1] = d[2];   // SSE to third
    best = id[0];
  }
  best = __shfl(best, 0);
  const float* er = E + (size_t)best * KD;
  *(float4*)(outF + (size_t)row * KD + lane * 8) = *(const float4*)(er + lane * 8);
  *(float4*)(outF + (size_t)row * KD + lane * 8 + 4) = *(const float4*)(er + lane * 8 + 4);
}

// 64-lane bitonic sort of a key (all 64 lanes carry real candidate keys)
__device__ __forceinline__ ull sort64(ull k, int lane) {
#pragma unroll
  for (int kk = 2; kk <= 64; kk <<= 1) {
#pragma unroll
    for (int j = kk >> 1; j > 0; j >>= 1) {
      ull o = __shfl_xor(k, j, 64);
      bool dirUp = (lane & kk) == 0;
      bool lower = (lane & j) == 0;
      bool pl = o < k;
      bool take = (dirUp == lower) ? pl : !pl;
      if (take) k = o;
    }
  }
  return k;
}

// two interleaved 64-lane bitonic sorts (independent chains -> 2x ILP on the
// shfl latency chain; k_mrf is latency-bound: r7 profile VALUBusy 7%)
__device__ __forceinline__ void sort64x2(ull& ka, ull& kb, int lane) {
#pragma unroll
  for (int kk = 2; kk <= 64; kk <<= 1) {
#pragma unroll
    for (int j = kk >> 1; j > 0; j >>= 1) {
      ull oa = __shfl_xor(ka, j, 64);
      ull ob = __shfl_xor(kb, j, 64);
      bool dirUp = (lane & kk) == 0;
      bool lower = (lane & j) == 0;
      bool ta = (dirUp == lower) ? (oa < ka) : !(oa < ka);
      bool tb = (dirUp == lower) ? (ob < kb) : !(ob < kb);
      if (ta) ka = oa;
      if (tb) kb = ob;
    }
  }
}

// ---------------------------------------------------------------------------
// Fused merge+refine, 2 ROWS PER WAVE: every latency chain (sort, E-gather,
// shuffle-reduce) is doubled into two independent chains the scheduler
// interleaves. X rows prefetched BEFORE the sorts (HBM latency under sort).
__global__ __launch_bounds__(256) void k_mrf(const float* __restrict__ X,
                                             const float* __restrict__ E,
                                             const ull* __restrict__ cand,
                                             float* __restrict__ outF,
                                             double* __restrict__ part) {
  const int lane = threadIdx.x & 63;
  const int wv = threadIdx.x >> 6;
  const int rA = blockIdx.x * 8 + wv * 2;
  const int rB = rA + 1;

  // issue cand + X loads up front (independent of each other)
  ull ka = cand[(size_t)rA * NCAND + lane];
  ull kb = cand[(size_t)rB * NCAND + lane];
  const float* xra = X + (size_t)rA * KD;
  const float* xrb = X + (size_t)rB * KD;
  float4 xa0 = *(const float4*)(xra + lane * 8);
  float4 xa1 = *(const float4*)(xra + lane * 8 + 4);
  float4 xb0 = *(const float4*)(xrb + lane * 8);
  float4 xb1 = *(const float4*)(xrb + lane * 8 + 4);

  sort64x2(ka, kb, lane);

  int ciA[NREF], ciB[NREF];
  ull keyA[NREF], keyB[NREF];
#pragma unroll
  for (int c = 0; c < NREF; ++c) {
    keyA[c] = __shfl(ka, c, 64);
    keyB[c] = __shfl(kb, c, 64);
    ciA[c] = (int)(keyA[c] & 0xffffffffull);
    ciB[c] = (int)(keyB[c] & 0xffffffffull);
  }
  // adaptive refine count (prefix-shaped since keys sorted ascending)
  float thrA = unpackd(keyA[2]) + RMARGIN;
  float thrB = unpackd(keyB[2]) + RMARGIN;
  int nA = 3 + (unpackd(keyA[3]) <= thrA ? 1 : 0) + (unpackd(keyA[4]) <= thrA ? 1 : 0);
  int nB = 3 + (unpackd(keyB[3]) <= thrB ? 1 : 0) + (unpackd(keyB[4]) <= thrB ? 1 : 0);

  double a[2 * NREF];
#pragma unroll
  for (int c = 0; c < NREF; ++c) {
    // row A candidate c
    if (c >= nA) { a[c] = 1.0e300; }
    else {
      const float* er = E + (size_t)ciA[c] * KD;
      float4 e0 = *(const float4*)(er + lane * 8);
      float4 e1 = *(const float4*)(er + lane * 8 + 4);
      double s = 0.0;
      double d0 = (double)e0.x - (double)xa0.x; s += d0 * d0;
      double d1 = (double)e0.y - (double)xa0.y; s += d1 * d1;
      double d2 = (double)e0.z - (double)xa0.z; s += d2 * d2;
      double d3 = (double)e0.w - (double)xa0.w; s += d3 * d3;
      double d4 = (double)e1.x - (double)xa1.x; s += d4 * d4;
      double d5 = (double)e1.y - (double)xa1.y; s += d5 * d5;
      double d6 = (double)e1.z - (double)xa1.z; s += d6 * d6;
      double d7 = (double)e1.w - (double)xa1.w; s += d7 * d7;
      a[c] = s;
    }
    // row B candidate c
    if (c >= nB) { a[NREF + c] = 1.0e300; }
    else {
      const float* er = E + (size_t)ciB[c] * KD;
      float4 e0 = *(const float4*)(er + lane * 8);
      float4 e1 = *(const float4*)(er + lane * 8 + 4);
      double s = 0.0;
      double d0 = (double)e0.x - (double)xb0.x; s += d0 * d0;
      double d1 = (double)e0.y - (double)xb0.y; s += d1 * d1;
      double d2 = (double)e0.z - (double)xb0.z; s += d2 * d2;
      double d3 = (double)e0.w - (double)xb0.w; s += d3 * d3;
      double d4 = (double)e1.x - (double)xb1.x; s += d4 * d4;
      double d5 = (double)e1.y - (double)xb1.y; s += d5 * d5;
      double d6 = (double)e1.z - (double)xb1.z; s += d6 * d6;
      double d7 = (double)e1.w - (double)xb1.w; s += d7 * d7;
      a[NREF + c] = s;
    }
  }
#pragma unroll
  for (int c = 0; c < 2 * NREF; ++c) {
    bool active = (c < NREF) ? (c < nA) : (c - NREF < nB);
    if (!active) continue;
#pragma unroll
    for (int off = 32; off; off >>= 1) a[c] += __shfl_down(a[c], off);
  }
  int bestA = 0, bestB = 0;
  if (lane == 0) {
    double d[NREF]; int id[NREF];
    // row A
#pragma unroll
    for (int c = 0; c < NREF; ++c) { d[c] = a[c]; id[c] = ciA[c]; }
    for (int i = 0; i < NREF; ++i)
      for (int j = i + 1; j < NREF; ++j)
        if (d[j] < d[i] || (d[j] == d[i] && id[j] < id[i])) {
          double dt = d[i]; d[i] = d[j]; d[j] = dt;
          int it = id[i]; id[i] = id[j]; id[j] = it;
        }
    part[(size_t)rA * 2] = d[0];
    part[(size_t)rA * 2 + 1] = d[2];
    bestA = id[0];
    // row B
#pragma unroll
    for (int c = 0; c < NREF; ++c) { d[c] = a[NREF + c]; id[c] = ciB[c]; }
    for (int i = 0; i < NREF; ++i)
      for (int j = i + 1; j < NREF; ++j)
        if (d[j] < d[i] || (d[j] == d[i] && id[j] < id[i])) {
          double dt = d[i]; d[i] = d[j]; d[j] = dt;
          int it = id[i]; id[i] = id[j]; id[j] = it;
        }
    part[(size_t)rB * 2] = d[0];
    part[(size_t)rB * 2 + 1] = d[2];
    bestB = id[0];
  }
  bestA = __shfl(bestA, 0);
  bestB = __shfl(bestB, 0);
  const float* ea = E + (size_t)bestA * KD;
  const float* eb = E + (size_t)bestB * KD;
  *(float4*)(outF + (size_t)rA * KD + lane * 8) = *(const float4*)(ea + lane * 8);
  *(float4*)(outF + (size_t)rA * KD + lane * 8 + 4) = *(const float4*)(ea + lane * 8 + 4);
  *(float4*)(outF + (size_t)rB * KD + lane * 8) = *(const float4*)(eb + lane * 8);
  *(float4*)(outF + (size_t)rB * KD + lane * 8 + 4) = *(const float4*)(eb + lane * 8 + 4);
}

// ---------------------------------------------------------------------------
// K_fin: one block x 1024 threads, deterministic reduction of RM pairs.
// (Separate 1-block kernel: cheaper than 3264 device-scope fences -- r7's
// last-block-fused variant cost +120 us from cross-XCD L2 flushes.)
__global__ __launch_bounds__(1024) void k_fin(const double* __restrict__ part,
                                              float* __restrict__ out) {
  const int tid = threadIdx.x;
  double a1 = 0.0, a3 = 0.0;
  for (int r = tid; r < RM; r += 1024) { a1 += part[2 * r]; a3 += part[2 * r + 1]; }
#pragma unroll
  for (int off = 32; off; off >>= 1) {
    a1 += __shfl_down(a1, off);
    a3 += __shfl_down(a3, off);
  }
  __shared__ double s1[16], s3[16];
  const int w = tid >> 6, lane = tid & 63;
  if (lane == 0) { s1[w] = a1; s3[w] = a3; }
  __syncthreads();
  if (tid == 0) {
    double S1 = 0.0, S3 = 0.0;
#pragma unroll
    for (int i = 0; i < 16; ++i) { S1 += s1[i]; S3 += s3[i]; }
    out[0] = (float)(1.0 - sqrt(S1 / S3));   // cp_score
    out[1] = (float)(0.25 * S1 / NELEM);     // k_loss
  }
}

// ---------------------------------------------------------------------------
// Fallback pair (cand in d_out tail): separate merge, then refine (full 5).
__global__ __launch_bounds__(256) void k_merge(const ull* __restrict__ cand,
                                               int* __restrict__ top8) {
  const int lane = threadIdx.x & 63;
  const int row = blockIdx.x * 4 + (threadIdx.x >> 6);
  ull k = lane < NCAND ? cand[(size_t)row * NCAND + lane] : ~0ull;
  k = sort64(k, lane);
  if (lane < NREF) top8[(size_t)row * 8 + lane] = (int)(k & 0xffffffffull);
}

__global__ __launch_bounds__(256) void k_refine_fb(const float* __restrict__ X,
                                                   const float* __restrict__ E,
                                                   const int* __restrict__ top8,
                                                   float* __restrict__ outF,
                                                   double* __restrict__ part) {
  const int row = blockIdx.x * 4 + (threadIdx.x >> 6);
  int ci[NREF];
#pragma unroll
  for (int c = 0; c < NREF; ++c) ci[c] = top8[(size_t)row * 8 + c];
  refine_core(X, E, ci, NREF, row, outF, part);
}

// ---------------------------------------------------------------------------
extern "C" void kernel_launch(void* const* d_in, const int* in_sizes, int n_in,
                              void* d_out, int out_size, void* d_ws, size_t ws_size,
                              hipStream_t stream) {
  const float* IP = (const float*)d_in[0];   // (256,51,512) fp32
  const float* EMB = (const float*)d_in[1];  // (2048,512) fp32
  float* out = (float*)d_out;

  // ws layout (16B-aligned): EN | part | top8 | Xh | Eh [| cand]
  char* ws = (char*)d_ws;
  size_t off = 0;
  float* EN = (float*)(ws + off);        off += NE * 4;
  double* part = (double*)(ws + off);    off += (size_t)RM * 2 * 8;  // 209 KB
  int* top8 = (int*)(ws + off);          off += (size_t)RM * 8 * 4;
  unsigned short* Xh = (unsigned short*)(ws + off); off += (size_t)RM * KD * 2;
  unsigned short* Ehs = (unsigned short*)(ws + off); off += (size_t)NE * KD * 2;
  ull* candWs = (ull*)(ws + off);        off += (size_t)RM * NCAND * 8;  // +6.7 MB
  const bool fused = ws_size >= off;     // ~22 MiB for the fused path

  // fallback: cand lives in d_out tail (consumed by k_merge before outF writes)
  ull* cand = fused ? candWs : (ull*)(out + 2);

  hipLaunchKernelGGL(k_prep, dim3(XB + EB + NB), dim3(256), 0, stream,
                     IP, EMB, Xh, Ehs, EN);
  hipLaunchKernelGGL(k_dist_bf16, dim3(GRID_D), dim3(256), 0, stream,
                     Xh, Ehs, EN, cand);
  if (fused) {
    hipLaunchKernelGGL(k_mrf, dim3(NTAIL2), dim3(256), 0, stream,
                       IP, EMB, cand, out + 2, part);
  } else {
    hipLaunchKernelGGL(k_merge, dim3(NTAIL), dim3(256), 0, stream, cand, top8);
    hipLaunchKernelGGL(k_refine_fb, dim3(NTAIL), dim3(256), 0, stream,
                       IP, EMB, top8, out + 2, part);
  }
  hipLaunchKernelGGL(k_fin, dim3(1), dim3(1024), 0, stream, part, out);
}

// Round 13
// 161.247 us; speedup vs baseline: 1.0411x; 1.0411x over previous
//
#include <hip/hip_runtime.h>
#include <hip/hip_bf16.h>
#include <math.h>

// Problem constants
#define RM 13056         // 256*17*3 rows of flat x
#define KD 512           // feature dim
#define NE 2048          // codebook entries
#define NELEM 6684672.0  // 256*51*512 elements for the mean

// dist kernel tiling
#define BM 128
#define BN 128
#define BK 32            // chunk-layout K-tile (fixed by prep layout)
#define NKT (KD / BK)    // 16 k-tiles
#define NBLK (NE / BN)   // 16 n-blocks
#define NCAND (NBLK * 4) // 64 candidates/row
#define NTAIL (RM / 4)   // 3264 tail blocks (4 rows each)
#define NREF 5           // max fp64-refined candidates (adaptive, usually 3)
#define RMARGIN 2.0f     // bf16 dist-error margin (~28 sigma; sigma ~0.07)
#define GRID_D ((RM / BM) * NBLK)   // 1632 = 8 * 204
#define XCD_CHUNK (GRID_D / 8)      // 204

typedef __attribute__((ext_vector_type(8))) short bf16x8;
typedef __attribute__((ext_vector_type(4))) float f32x4;
typedef unsigned long long ull;

// async global->LDS, 16B per lane; lds base wave-uniform, HW appends lane*16 (m104)
__device__ __forceinline__ void dma16(const void* g, void* l) {
  __builtin_amdgcn_global_load_lds((const __attribute__((address_space(1))) void*)g,
                                   (__attribute__((address_space(3))) void*)l, 16, 0, 0);
}

// order-preserving (dist, idx) -> u64 key: ascending u64 == lexicographic (d, ix)
__device__ __forceinline__ ull packdi(float d, int ix) {
  unsigned u = __float_as_uint(d);
  u ^= (unsigned)((int)u >> 31) | 0x80000000u;
  return ((ull)u << 32) | (unsigned)ix;
}

// inverse of packdi's float transform (key high word -> original float)
__device__ __forceinline__ float unpackd(ull key) {
  unsigned u = (unsigned)(key >> 32);
  u = (u & 0x80000000u) ? (u ^ 0x80000000u) : ~u;
  return __uint_as_float(u);
}

// ---------------------------------------------------------------------------
// K_prep: fused preprocessing. Single-bf16 candidate path: only hi parts.
#define XB (RM * 64 / 256)   // 3264
#define EB (NE * 64 / 256)   // 512
#define NB (NE / 4)          // 512
__device__ __forceinline__ void split_chunks(const float* __restrict__ src,
                                             unsigned short* __restrict__ hi,
                                             int rows, int o) {
  int t4 = o >> 2;
  int kt = t4 / rows;
  int row = t4 - kt * rows;
  int slot = o & 3;
  int q = slot ^ ((row >> 1) & 3);
  const float* s = src + (size_t)row * KD + kt * 32 + q * 8;
  float4 v0 = ((const float4*)s)[0];
  float4 v1 = ((const float4*)s)[1];
  float f[8] = {v0.x, v0.y, v0.z, v0.w, v1.x, v1.y, v1.z, v1.w};
  unsigned hh[4];
#pragma unroll
  for (int j = 0; j < 4; ++j) {
    __hip_bfloat16 b0 = __float2bfloat16(f[2 * j]);
    __hip_bfloat16 b1 = __float2bfloat16(f[2 * j + 1]);
    hh[j] = (unsigned)*(unsigned short*)&b0 | ((unsigned)*(unsigned short*)&b1 << 16);
  }
  ((uint4*)hi)[o] = make_uint4(hh[0], hh[1], hh[2], hh[3]);
}

__global__ __launch_bounds__(256) void k_prep(const float* __restrict__ X,
                                              const float* __restrict__ E,
                                              unsigned short* __restrict__ Xh,
                                              unsigned short* __restrict__ Eh,
                                              float* __restrict__ EN) {
  const int b = blockIdx.x, tid = threadIdx.x;
  if (b < XB) {
    split_chunks(X, Xh, RM, b * 256 + tid);
  } else if (b < XB + EB) {
    split_chunks(E, Eh, NE, (b - XB) * 256 + tid);
  } else {
    int n = (b - XB - EB) * 4 + (tid >> 6);
    int lane = tid & 63;
    const float* e = E + (size_t)n * KD;
    float s = 0.f;
#pragma unroll
    for (int j = 0; j < 8; ++j) { float v = e[lane + 64 * j]; s += v * v; }
#pragma unroll
    for (int off = 32; off; off >>= 1) s += __shfl_down(s, off);
    if (lane == 0) EN[n] = s;
  }
}

// ---------------------------------------------------------------------------
// LDS chunk addressing (ushort elem offset): chunk q of local row at slot
// q ^ ((row>>1)&3). Conflicts measured 0.
__device__ __forceinline__ int chidx(int row, int q) {
  return (row * 4 + (q ^ ((row >> 1) & 3))) * 8;
}

// K1: single-bf16 MFMA distance tile, BM=128 x BN=128 per block.
// Round-9/10 measured-best: saddr-form staging (r8's VGPR pointer hoisting
// cost 60->80 us -- do not hoist) + XCD-chunked bijective swizzle
// (r10: FETCH 54.4 -> 15.5 MB, the compulsory ideal). Reproduced 58-61 us
// across 4 containers; 7 schedule variants (r1/r2/r4/r5/r8 + dbuf/stream)
// all regressed -- structure-capped.
__global__ __launch_bounds__(256, 4) void k_dist_bf16(
    const unsigned short* __restrict__ Xh,
    const unsigned short* __restrict__ Eh,
    const float* __restrict__ EN, ull* __restrict__ cand) {
  __shared__ __align__(16) unsigned short sXh[2][BM * BK];  // 2 x 8 KB
  __shared__ __align__(16) unsigned short sEh[2][BN * BK];  // 2 x 8 KB
  __shared__ float sEN[BN];

  const int tid = threadIdx.x;
  const int lane = tid & 63;
  const int w = tid >> 6;
  const int quad = lane >> 4;
  const int lx = lane & 15;
  const int nbid = (blockIdx.x & 7) * XCD_CHUNK + (blockIdx.x >> 3);
  const int by = nbid & (NBLK - 1);
  const int bx = nbid >> 4;
  const int rowBase = bx * BM;
  const int colBase = by * BN;

  if (tid < BN) sEN[tid] = EN[colBase + tid];

  // frag LDS offsets (constant per lane)
  int aidx[2], bidx[8];
#pragma unroll
  for (int mt = 0; mt < 2; ++mt) aidx[mt] = chidx(w * 32 + mt * 16 + lx, quad);
#pragma unroll
  for (int ct = 0; ct < 8; ++ct) bidx[ct] = chidx(ct * 16 + lx, quad);

  f32x4 acc[2][8];
#pragma unroll
  for (int mt = 0; mt < 2; ++mt)
#pragma unroll
    for (int ct = 0; ct < 8; ++ct) acc[mt][ct] = (f32x4){0.f, 0.f, 0.f, 0.f};

  // stage one 32-K tile (16 KB) into half-buffer h: 4 dma16/thread
  auto stage = [&](int h, int kt) {
    const size_t xbase = ((size_t)kt * RM + rowBase) * 4;   // chunk units
    const size_t ebase = ((size_t)kt * NE + colBase) * 4;
#pragma unroll
    for (int i = 0; i < 2; ++i) {   // X: 512 chunks, E: 512 chunks
      const int c = i * 256 + tid;
      const int ldsOff = (i * 256 + w * 64) * 8;
      dma16(Xh + (xbase + c) * 8, &sXh[h][ldsOff]);
      dma16(Eh + (ebase + c) * 8, &sEh[h][ldsOff]);
    }
  };

  // compute one 32-K tile from half-buffer h: 10 ds_read_b128 + 16 MFMA / wave
  auto compute = [&](int h) {
    bf16x8 Ah[2];
#pragma unroll
    for (int mt = 0; mt < 2; ++mt) Ah[mt] = *(const bf16x8*)&sXh[h][aidx[mt]];
#pragma unroll
    for (int ct = 0; ct < 8; ++ct) {
      bf16x8 Bh = *(const bf16x8*)&sEh[h][bidx[ct]];
#pragma unroll
      for (int mt = 0; mt < 2; ++mt)
        acc[mt][ct] = __builtin_amdgcn_mfma_f32_16x16x32_bf16(Ah[mt], Bh, acc[mt][ct], 0, 0, 0);
    }
  };

#pragma unroll 1
  for (int kt2 = 0; kt2 < NKT / 2; ++kt2) {
    __syncthreads();  // previous iteration's readers done
    stage(0, kt2 * 2);
    stage(1, kt2 * 2 + 1);
    __syncthreads();  // compiler drains vmcnt before barrier
    compute(0);
    compute(1);
  }

  // epilogue: C/D layout col=lane&15, row=quad*4+reg (m89/m91)
  float en[8];
#pragma unroll
  for (int ct = 0; ct < 8; ++ct) en[ct] = sEN[ct * 16 + lx];

#pragma unroll
  for (int mt = 0; mt < 2; ++mt) {
#pragma unroll
    for (int j = 0; j < 4; ++j) {
      float a0 = 3.4e38f, a1 = 3.4e38f, a2 = 3.4e38f, a3 = 3.4e38f;
      int i0 = 0x7fffffff, i1 = i0, i2 = i0, i3 = i0;
#pragma unroll
      for (int ct = 0; ct < 8; ++ct) {
        float d = en[ct] - 2.0f * acc[mt][ct][j];
        int ix = colBase + ct * 16 + lx;
        // ascending idx + strict < keeps the lower index on ties
        if (d < a3) {
          if (d < a2) { a3 = a2; i3 = i2;
            if (d < a1) { a2 = a1; i2 = i1;
              if (d < a0) { a1 = a0; i1 = i0; a0 = d; i0 = ix; }
              else { a1 = d; i1 = ix; } }
            else { a2 = d; i2 = ix; } }
          else { a3 = d; i3 = ix; }
        }
      }
      // 4-round min-extraction across the 16-lane group (keys unique per row)
      ull k0 = packdi(a0, i0), k1 = packdi(a1, i1);
      ull k2 = packdi(a2, i2), k3 = packdi(a3, i3);
      int pos = 0;
      ull res[4];
#pragma unroll
      for (int r = 0; r < 4; ++r) {
        ull h = pos == 0 ? k0 : pos == 1 ? k1 : pos == 2 ? k2 : pos == 3 ? k3 : ~0ull;
        ull m = h;
#pragma unroll
        for (int step = 1; step < 16; step <<= 1) {
          ull o = __shfl_xor(m, step, 16);
          m = o < m ? o : m;
        }
        res[r] = m;
        pos += (h == m) ? 1 : 0;
      }
      if (lx == 0) {
        int row = rowBase + w * 32 + mt * 16 + quad * 4 + j;
        ull* dst = cand + (size_t)row * NCAND + by * 4;
        dst[0] = res[0]; dst[1] = res[1]; dst[2] = res[2]; dst[3] = res[3];
      }
    }
  }
}

// ---------------------------------------------------------------------------
// fp64 refine of ci[0..nref) for `row` with X already in registers.
// WAVE-LOCAL (r8: no block coupling; wave-decoupled part[] writes).
__device__ __forceinline__ void refine_x(const float* __restrict__ E,
                                         float4 x0, float4 x1,
                                         const int* ci, int nref, int row,
                                         float* __restrict__ outF,
                                         double* __restrict__ part) {
  const int lane = threadIdx.x & 63;
  double a[NREF];
#pragma unroll
  for (int c = 0; c < NREF; ++c) {
    if (c >= nref) { a[c] = 1.0e300; continue; }   // wave-uniform skip
    const float* er = E + (size_t)ci[c] * KD;
    float4 e0 = *(const float4*)(er + lane * 8);
    float4 e1 = *(const float4*)(er + lane * 8 + 4);
    double s = 0.0;
    double d0 = (double)e0.x - (double)x0.x; s += d0 * d0;
    double d1 = (double)e0.y - (double)x0.y; s += d1 * d1;
    double d2 = (double)e0.z - (double)x0.z; s += d2 * d2;
    double d3 = (double)e0.w - (double)x0.w; s += d3 * d3;
    double d4 = (double)e1.x - (double)x1.x; s += d4 * d4;
    double d5 = (double)e1.y - (double)x1.y; s += d5 * d5;
    double d6 = (double)e1.z - (double)x1.z; s += d6 * d6;
    double d7 = (double)e1.w - (double)x1.w; s += d7 * d7;
    a[c] = s;
  }
#pragma unroll
  for (int c = 0; c < NREF; ++c) {
    if (c >= nref) continue;
#pragma unroll
    for (int off = 32; off; off >>= 1) a[c] += __shfl_down(a[c], off);
  }
  int best = 0;
  if (lane == 0) {
    double d[NREF]; int id[NREF];
#pragma unroll
    for (int c = 0; c < NREF; ++c) { d[c] = a[c]; id[c] = ci[c]; }
    for (int i = 0; i < NREF; ++i)
      for (int j = i + 1; j < NREF; ++j)
        if (d[j] < d[i] || (d[j] == d[i] && id[j] < id[i])) {
          double dt = d[i]; d[i] = d[j]; d[j] = dt;
          int it = id[i]; id[i] = id[j]; id[j] = it;
        }
    part[(size_t)row * 2] = d[0];       // SSE to nearest
    part[(size_t)row * 2 + 1] = d[2];   // SSE to third
    best = id[0];
  }
  best = __shfl(best, 0);
  const float* er = E + (size_t)best * KD;
  *(float4*)(outF + (size_t)row * KD + lane * 8) = *(const float4*)(er + lane * 8);
  *(float4*)(outF + (size_t)row * KD + lane * 8 + 4) = *(const float4*)(er + lane * 8 + 4);
}

// 64-lane bitonic sort of a key (all 64 lanes carry real candidate keys)
__device__ __forceinline__ ull sort64(ull k, int lane) {
#pragma unroll
  for (int kk = 2; kk <= 64; kk <<= 1) {
#pragma unroll
    for (int j = kk >> 1; j > 0; j >>= 1) {
      ull o = __shfl_xor(k, j, 64);
      bool dirUp = (lane & kk) == 0;
      bool lower = (lane & j) == 0;
      bool pl = o < k;
      bool take = (dirUp == lower) ? pl : !pl;
      if (take) k = o;
    }
  }
  return k;
}

// ---------------------------------------------------------------------------
// Fused merge+refine, 1 row/wave (r11 measured-best form; r12's 2-row ILP
// variant regressed +5 us from register pressure). Single addition: X-row
// loads ISSUED BEFORE sort64 -- ~900-cyc HBM latency hides under the
// 21-stage pure-VALU shfl sort at a cost of 8 live VGPRs.
__global__ __launch_bounds__(256) void k_mrf(const float* __restrict__ X,
                                             const float* __restrict__ E,
                                             const ull* __restrict__ cand,
                                             float* __restrict__ outF,
                                             double* __restrict__ part) {
  const int lane = threadIdx.x & 63;
  const int row = blockIdx.x * 4 + (threadIdx.x >> 6);
  // issue cand + X loads up front (independent; X use is after the sort)
  ull k = cand[(size_t)row * NCAND + lane];
  const float* xr = X + (size_t)row * KD;
  float4 x0 = *(const float4*)(xr + lane * 8);
  float4 x1 = *(const float4*)(xr + lane * 8 + 4);

  k = sort64(k, lane);
  int ci[NREF];
  ull key[NREF];
#pragma unroll
  for (int c = 0; c < NREF; ++c) {
    key[c] = __shfl(k, c, 64);
    ci[c] = (int)(key[c] & 0xffffffffull);
  }
  // adaptive refine count (prefix-shaped since keys sorted ascending)
  float thr = unpackd(key[2]) + RMARGIN;
  int nref = 3 + (unpackd(key[3]) <= thr ? 1 : 0) + (unpackd(key[4]) <= thr ? 1 : 0);
  refine_x(E, x0, x1, ci, nref, row, outF, part);
}

// ---------------------------------------------------------------------------
// K_fin: one block x 1024 threads, deterministic reduction of RM pairs.
// (Separate 1-block kernel: cheaper than 3264 device-scope fences -- r7's
// last-block-fused variant cost +120 us from cross-XCD L2 flushes.)
__global__ __launch_bounds__(1024) void k_fin(const double* __restrict__ part,
                                              float* __restrict__ out) {
  const int tid = threadIdx.x;
  double a1 = 0.0, a3 = 0.0;
  for (int r = tid; r < RM; r += 1024) { a1 += part[2 * r]; a3 += part[2 * r + 1]; }
#pragma unroll
  for (int off = 32; off; off >>= 1) {
    a1 += __shfl_down(a1, off);
    a3 += __shfl_down(a3, off);
  }
  __shared__ double s1[16], s3[16];
  const int w = tid >> 6, lane = tid & 63;
  if (lane == 0) { s1[w] = a1; s3[w] = a3; }
  __syncthreads();
  if (tid == 0) {
    double S1 = 0.0, S3 = 0.0;
#pragma unroll
    for (int i = 0; i < 16; ++i) { S1 += s1[i]; S3 += s3[i]; }
    out[0] = (float)(1.0 - sqrt(S1 / S3));   // cp_score
    out[1] = (float)(0.25 * S1 / NELEM);     // k_loss
  }
}

// ---------------------------------------------------------------------------
// Fallback pair (cand in d_out tail): separate merge, then refine (full 5).
__global__ __launch_bounds__(256) void k_merge(const ull* __restrict__ cand,
                                               int* __restrict__ top8) {
  const int lane = threadIdx.x & 63;
  const int row = blockIdx.x * 4 + (threadIdx.x >> 6);
  ull k = lane < NCAND ? cand[(size_t)row * NCAND + lane] : ~0ull;
  k = sort64(k, lane);
  if (lane < NREF) top8[(size_t)row * 8 + lane] = (int)(k & 0xffffffffull);
}

__global__ __launch_bounds__(256) void k_refine_fb(const float* __restrict__ X,
                                                   const float* __restrict__ E,
                                                   const int* __restrict__ top8,
                                                   float* __restrict__ outF,
                                                   double* __restrict__ part) {
  const int lane = threadIdx.x & 63;
  const int row = blockIdx.x * 4 + (threadIdx.x >> 6);
  int ci[NREF];
#pragma unroll
  for (int c = 0; c < NREF; ++c) ci[c] = top8[(size_t)row * 8 + c];
  const float* xr = X + (size_t)row * KD;
  float4 x0 = *(const float4*)(xr + lane * 8);
  float4 x1 = *(const float4*)(xr + lane * 8 + 4);
  refine_x(E, x0, x1, ci, NREF, row, outF, part);
}

// ---------------------------------------------------------------------------
extern "C" void kernel_launch(void* const* d_in, const int* in_sizes, int n_in,
                              void* d_out, int out_size, void* d_ws, size_t ws_size,
                              hipStream_t stream) {
  const float* IP = (const float*)d_in[0];   // (256,51,512) fp32
  const float* EMB = (const float*)d_in[1];  // (2048,512) fp32
  float* out = (float*)d_out;

  // ws layout (16B-aligned): EN | part | top8 | Xh | Eh [| cand]
  char* ws = (char*)d_ws;
  size_t off = 0;
  float* EN = (float*)(ws + off);        off += NE * 4;
  double* part = (double*)(ws + off);    off += (size_t)RM * 2 * 8;  // 209 KB
  int* top8 = (int*)(ws + off);          off += (size_t)RM * 8 * 4;
  unsigned short* Xh = (unsigned short*)(ws + off); off += (size_t)RM * KD * 2;
  unsigned short* Ehs = (unsigned short*)(ws + off); off += (size_t)NE * KD * 2;
  ull* candWs = (ull*)(ws + off);        off += (size_t)RM * NCAND * 8;  // +6.7 MB
  const bool fused = ws_size >= off;     // ~22 MiB for the fused path

  // fallback: cand lives in d_out tail (consumed by k_merge before outF writes)
  ull* cand = fused ? candWs : (ull*)(out + 2);

  hipLaunchKernelGGL(k_prep, dim3(XB + EB + NB), dim3(256), 0, stream,
                     IP, EMB, Xh, Ehs, EN);
  hipLaunchKernelGGL(k_dist_bf16, dim3(GRID_D), dim3(256), 0, stream,
                     Xh, Ehs, EN, cand);
  if (fused) {
    hipLaunchKernelGGL(k_mrf, dim3(NTAIL), dim3(256), 0, stream,
                       IP, EMB, cand, out + 2, part);
  } else {
    hipLaunchKernelGGL(k_merge, dim3(NTAIL), dim3(256), 0, stream, cand, top8);
    hipLaunchKernelGGL(k_refine_fb, dim3(NTAIL), dim3(256), 0, stream,
                       IP, EMB, top8, out + 2, part);
  }
  hipLaunchKernelGGL(k_fin, dim3(1), dim3(1024), 0, stream, part, out);
}

// Round 14
// 157.618 us; speedup vs baseline: 1.0651x; 1.0230x over previous
//
#include <hip/hip_runtime.h>
#include <hip/hip_bf16.h>
#include <math.h>

// Problem constants
#define RM 13056         // 256*17*3 rows of flat x
#define KD 512           // feature dim
#define NE 2048          // codebook entries
#define NELEM 6684672.0  // 256*51*512 elements for the mean

// dist kernel tiling
#define BM 128
#define BN 128
#define BK 32            // chunk-layout K-tile (fixed by prep layout)
#define NKT (KD / BK)    // 16 k-tiles
#define NBLK (NE / BN)   // 16 n-blocks
#define NCAND (NBLK * 4) // 64 candidates/row
#define NTAIL (RM / 4)   // 3264 tail blocks (4 rows each)
#define NREF 5           // max fp64-refined candidates (adaptive, usually 3)
#define RMARGIN 2.0f     // bf16 dist-error margin (~28 sigma; sigma ~0.07)
#define GRID_D ((RM / BM) * NBLK)   // 1632 = 8 * 204
#define XCD_CHUNK (GRID_D / 8)      // 204

typedef __attribute__((ext_vector_type(8))) short bf16x8;
typedef __attribute__((ext_vector_type(4))) float f32x4;
typedef unsigned long long ull;

// async global->LDS, 16B per lane; lds base wave-uniform, HW appends lane*16 (m104)
__device__ __forceinline__ void dma16(const void* g, void* l) {
  __builtin_amdgcn_global_load_lds((const __attribute__((address_space(1))) void*)g,
                                   (__attribute__((address_space(3))) void*)l, 16, 0, 0);
}

// order-preserving (dist, idx) -> u64 key: ascending u64 == lexicographic (d, ix)
__device__ __forceinline__ ull packdi(float d, int ix) {
  unsigned u = __float_as_uint(d);
  u ^= (unsigned)((int)u >> 31) | 0x80000000u;
  return ((ull)u << 32) | (unsigned)ix;
}

// inverse of packdi's float transform (key high word -> original float)
__device__ __forceinline__ float unpackd(ull key) {
  unsigned u = (unsigned)(key >> 32);
  u = (u & 0x80000000u) ? (u ^ 0x80000000u) : ~u;
  return __uint_as_float(u);
}

// ---------------------------------------------------------------------------
// K_prep: fused preprocessing. Single-bf16 candidate path: only hi parts.
#define XB (RM * 64 / 256)   // 3264
#define EB (NE * 64 / 256)   // 512
#define NB (NE / 4)          // 512
__device__ __forceinline__ void split_chunks(const float* __restrict__ src,
                                             unsigned short* __restrict__ hi,
                                             int rows, int o) {
  int t4 = o >> 2;
  int kt = t4 / rows;
  int row = t4 - kt * rows;
  int slot = o & 3;
  int q = slot ^ ((row >> 1) & 3);
  const float* s = src + (size_t)row * KD + kt * 32 + q * 8;
  float4 v0 = ((const float4*)s)[0];
  float4 v1 = ((const float4*)s)[1];
  float f[8] = {v0.x, v0.y, v0.z, v0.w, v1.x, v1.y, v1.z, v1.w};
  unsigned hh[4];
#pragma unroll
  for (int j = 0; j < 4; ++j) {
    __hip_bfloat16 b0 = __float2bfloat16(f[2 * j]);
    __hip_bfloat16 b1 = __float2bfloat16(f[2 * j + 1]);
    hh[j] = (unsigned)*(unsigned short*)&b0 | ((unsigned)*(unsigned short*)&b1 << 16);
  }
  ((uint4*)hi)[o] = make_uint4(hh[0], hh[1], hh[2], hh[3]);
}

__global__ __launch_bounds__(256) void k_prep(const float* __restrict__ X,
                                              const float* __restrict__ E,
                                              unsigned short* __restrict__ Xh,
                                              unsigned short* __restrict__ Eh,
                                              float* __restrict__ EN) {
  const int b = blockIdx.x, tid = threadIdx.x;
  if (b < XB) {
    split_chunks(X, Xh, RM, b * 256 + tid);
  } else if (b < XB + EB) {
    split_chunks(E, Eh, NE, (b - XB) * 256 + tid);
  } else {
    int n = (b - XB - EB) * 4 + (tid >> 6);
    int lane = tid & 63;
    const float* e = E + (size_t)n * KD;
    float s = 0.f;
#pragma unroll
    for (int j = 0; j < 8; ++j) { float v = e[lane + 64 * j]; s += v * v; }
#pragma unroll
    for (int off = 32; off; off >>= 1) s += __shfl_down(s, off);
    if (lane == 0) EN[n] = s;
  }
}

// ---------------------------------------------------------------------------
// LDS chunk addressing (ushort elem offset): chunk q of local row at slot
// q ^ ((row>>1)&3). Conflicts measured 0.
__device__ __forceinline__ int chidx(int row, int q) {
  return (row * 4 + (q ^ ((row >> 1) & 3))) * 8;
}

// K1: single-bf16 MFMA distance tile, BM=128 x BN=128 per block.
// saddr-form staging (r8: VGPR pointer hoisting cost 60->80 -- do not hoist)
// + XCD-chunked bijective swizzle (r10: FETCH 54.4 -> 15.5 MB, ideal).
// NEW (last untested schedule cell): covered-drain single-barrier loop --
//   { stage(next -> other buf); compute(cur buf); __syncthreads(); }
// The drain (vmcnt0/lgkmcnt0 at the sync) now has ~500 cyc of ds_read+MFMA
// between load-issue and barrier, vs r13's zero-covering-work drain after
// stage x2. Race-free: compute(buf) and the overwriting stage(buf) are
// separated by exactly one sync (lgkmcnt side); stage(buf)->compute(buf)
// by one sync (vmcnt side). r4 tested this ordering and LOST, but at
// 2 blocks/CU with 24 KB bursts; at 4 blocks/CU with 16 KB tiles the
// failure mechanism (insufficient covering work + TLP) is weakened.
__global__ __launch_bounds__(256, 4) void k_dist_bf16(
    const unsigned short* __restrict__ Xh,
    const unsigned short* __restrict__ Eh,
    const float* __restrict__ EN, ull* __restrict__ cand) {
  __shared__ __align__(16) unsigned short sXh[2][BM * BK];  // 2 x 8 KB
  __shared__ __align__(16) unsigned short sEh[2][BN * BK];  // 2 x 8 KB
  __shared__ float sEN[BN];

  const int tid = threadIdx.x;
  const int lane = tid & 63;
  const int w = tid >> 6;
  const int quad = lane >> 4;
  const int lx = lane & 15;
  const int nbid = (blockIdx.x & 7) * XCD_CHUNK + (blockIdx.x >> 3);
  const int by = nbid & (NBLK - 1);
  const int bx = nbid >> 4;
  const int rowBase = bx * BM;
  const int colBase = by * BN;

  if (tid < BN) sEN[tid] = EN[colBase + tid];

  // frag LDS offsets (constant per lane)
  int aidx[2], bidx[8];
#pragma unroll
  for (int mt = 0; mt < 2; ++mt) aidx[mt] = chidx(w * 32 + mt * 16 + lx, quad);
#pragma unroll
  for (int ct = 0; ct < 8; ++ct) bidx[ct] = chidx(ct * 16 + lx, quad);

  f32x4 acc[2][8];
#pragma unroll
  for (int mt = 0; mt < 2; ++mt)
#pragma unroll
    for (int ct = 0; ct < 8; ++ct) acc[mt][ct] = (f32x4){0.f, 0.f, 0.f, 0.f};

  // stage one 32-K tile (16 KB) into half-buffer h: 4 dma16/thread
  auto stage = [&](int h, int kt) {
    const size_t xbase = ((size_t)kt * RM + rowBase) * 4;   // chunk units
    const size_t ebase = ((size_t)kt * NE + colBase) * 4;
#pragma unroll
    for (int i = 0; i < 2; ++i) {   // X: 512 chunks, E: 512 chunks
      const int c = i * 256 + tid;
      const int ldsOff = (i * 256 + w * 64) * 8;
      dma16(Xh + (xbase + c) * 8, &sXh[h][ldsOff]);
      dma16(Eh + (ebase + c) * 8, &sEh[h][ldsOff]);
    }
  };

  // compute one 32-K tile from half-buffer h: 10 ds_read_b128 + 16 MFMA / wave
  auto compute = [&](int h) {
    bf16x8 Ah[2];
#pragma unroll
    for (int mt = 0; mt < 2; ++mt) Ah[mt] = *(const bf16x8*)&sXh[h][aidx[mt]];
#pragma unroll
    for (int ct = 0; ct < 8; ++ct) {
      bf16x8 Bh = *(const bf16x8*)&sEh[h][bidx[ct]];
#pragma unroll
      for (int mt = 0; mt < 2; ++mt)
        acc[mt][ct] = __builtin_amdgcn_mfma_f32_16x16x32_bf16(Ah[mt], Bh, acc[mt][ct], 0, 0, 0);
    }
  };

  stage(0, 0);
  __syncthreads();  // prologue: buf0 staged (also orders sEN writes)

#pragma unroll 1
  for (int kt = 0; kt < NKT; ++kt) {
    if (kt + 1 < NKT) stage((kt + 1) & 1, kt + 1);  // issue into other buf
    compute(kt & 1);                                // covering work
    __syncthreads();                                // drain covered by compute
  }

  // epilogue: C/D layout col=lane&15, row=quad*4+reg (m89/m91)
  float en[8];
#pragma unroll
  for (int ct = 0; ct < 8; ++ct) en[ct] = sEN[ct * 16 + lx];

#pragma unroll
  for (int mt = 0; mt < 2; ++mt) {
#pragma unroll
    for (int j = 0; j < 4; ++j) {
      float a0 = 3.4e38f, a1 = 3.4e38f, a2 = 3.4e38f, a3 = 3.4e38f;
      int i0 = 0x7fffffff, i1 = i0, i2 = i0, i3 = i0;
#pragma unroll
      for (int ct = 0; ct < 8; ++ct) {
        float d = en[ct] - 2.0f * acc[mt][ct][j];
        int ix = colBase + ct * 16 + lx;
        // ascending idx + strict < keeps the lower index on ties
        if (d < a3) {
          if (d < a2) { a3 = a2; i3 = i2;
            if (d < a1) { a2 = a1; i2 = i1;
              if (d < a0) { a1 = a0; i1 = i0; a0 = d; i0 = ix; }
              else { a1 = d; i1 = ix; } }
            else { a2 = d; i2 = ix; } }
          else { a3 = d; i3 = ix; }
        }
      }
      // 4-round min-extraction across the 16-lane group (keys unique per row)
      ull k0 = packdi(a0, i0), k1 = packdi(a1, i1);
      ull k2 = packdi(a2, i2), k3 = packdi(a3, i3);
      int pos = 0;
      ull res[4];
#pragma unroll
      for (int r = 0; r < 4; ++r) {
        ull h = pos == 0 ? k0 : pos == 1 ? k1 : pos == 2 ? k2 : pos == 3 ? k3 : ~0ull;
        ull m = h;
#pragma unroll
        for (int step = 1; step < 16; step <<= 1) {
          ull o = __shfl_xor(m, step, 16);
          m = o < m ? o : m;
        }
        res[r] = m;
        pos += (h == m) ? 1 : 0;
      }
      if (lx == 0) {
        int row = rowBase + w * 32 + mt * 16 + quad * 4 + j;
        ull* dst = cand + (size_t)row * NCAND + by * 4;
        dst[0] = res[0]; dst[1] = res[1]; dst[2] = res[2]; dst[3] = res[3];
      }
    }
  }
}

// ---------------------------------------------------------------------------
// fp64 refine of ci[0..nref) for `row` with X already in registers.
// WAVE-LOCAL (r8: no block coupling; wave-decoupled part[] writes).
__device__ __forceinline__ void refine_x(const float* __restrict__ E,
                                         float4 x0, float4 x1,
                                         const int* ci, int nref, int row,
                                         float* __restrict__ outF,
                                         double* __restrict__ part) {
  const int lane = threadIdx.x & 63;
  double a[NREF];
#pragma unroll
  for (int c = 0; c < NREF; ++c) {
    if (c >= nref) { a[c] = 1.0e300; continue; }   // wave-uniform skip
    const float* er = E + (size_t)ci[c] * KD;
    float4 e0 = *(const float4*)(er + lane * 8);
    float4 e1 = *(const float4*)(er + lane * 8 + 4);
    double s = 0.0;
    double d0 = (double)e0.x - (double)x0.x; s += d0 * d0;
    double d1 = (double)e0.y - (double)x0.y; s += d1 * d1;
    double d2 = (double)e0.z - (double)x0.z; s += d2 * d2;
    double d3 = (double)e0.w - (double)x0.w; s += d3 * d3;
    double d4 = (double)e1.x - (double)x1.x; s += d4 * d4;
    double d5 = (double)e1.y - (double)x1.y; s += d5 * d5;
    double d6 = (double)e1.z - (double)x1.z; s += d6 * d6;
    double d7 = (double)e1.w - (double)x1.w; s += d7 * d7;
    a[c] = s;
  }
#pragma unroll
  for (int c = 0; c < NREF; ++c) {
    if (c >= nref) continue;
#pragma unroll
    for (int off = 32; off; off >>= 1) a[c] += __shfl_down(a[c], off);
  }
  int best = 0;
  if (lane == 0) {
    double d[NREF]; int id[NREF];
#pragma unroll
    for (int c = 0; c < NREF; ++c) { d[c] = a[c]; id[c] = ci[c]; }
    for (int i = 0; i < NREF; ++i)
      for (int j = i + 1; j < NREF; ++j)
        if (d[j] < d[i] || (d[j] == d[i] && id[j] < id[i])) {
          double dt = d[i]; d[i] = d[j]; d[j] = dt;
          int it = id[i]; id[i] = id[j]; id[j] = it;
        }
    part[(size_t)row * 2] = d[0];       // SSE to nearest
    part[(size_t)row * 2 + 1] = d[2];   // SSE to third
    best = id[0];
  }
  best = __shfl(best, 0);
  const float* er = E + (size_t)best * KD;
  *(float4*)(outF + (size_t)row * KD + lane * 8) = *(const float4*)(er + lane * 8);
  *(float4*)(outF + (size_t)row * KD + lane * 8 + 4) = *(const float4*)(er + lane * 8 + 4);
}

// 64-lane bitonic sort of a key (all 64 lanes carry real candidate keys)
__device__ __forceinline__ ull sort64(ull k, int lane) {
#pragma unroll
  for (int kk = 2; kk <= 64; kk <<= 1) {
#pragma unroll
    for (int j = kk >> 1; j > 0; j >>= 1) {
      ull o = __shfl_xor(k, j, 64);
      bool dirUp = (lane & kk) == 0;
      bool lower = (lane & j) == 0;
      bool pl = o < k;
      bool take = (dirUp == lower) ? pl : !pl;
      if (take) k = o;
    }
  }
  return k;
}

// ---------------------------------------------------------------------------
// Fused merge+refine, 1 row/wave (r11/r13 measured-best form; r12's 2-row
// ILP variant regressed +5 us from register pressure). X-row loads issued
// before sort64 (HBM latency under the pure-VALU shfl sort).
__global__ __launch_bounds__(256) void k_mrf(const float* __restrict__ X,
                                             const float* __restrict__ E,
                                             const ull* __restrict__ cand,
                                             float* __restrict__ outF,
                                             double* __restrict__ part) {
  const int lane = threadIdx.x & 63;
  const int row = blockIdx.x * 4 + (threadIdx.x >> 6);
  // issue cand + X loads up front (independent; X use is after the sort)
  ull k = cand[(size_t)row * NCAND + lane];
  const float* xr = X + (size_t)row * KD;
  float4 x0 = *(const float4*)(xr + lane * 8);
  float4 x1 = *(const float4*)(xr + lane * 8 + 4);

  k = sort64(k, lane);
  int ci[NREF];
  ull key[NREF];
#pragma unroll
  for (int c = 0; c < NREF; ++c) {
    key[c] = __shfl(k, c, 64);
    ci[c] = (int)(key[c] & 0xffffffffull);
  }
  // adaptive refine count (prefix-shaped since keys sorted ascending)
  float thr = unpackd(key[2]) + RMARGIN;
  int nref = 3 + (unpackd(key[3]) <= thr ? 1 : 0) + (unpackd(key[4]) <= thr ? 1 : 0);
  refine_x(E, x0, x1, ci, nref, row, outF, part);
}

// ---------------------------------------------------------------------------
// K_fin: one block x 1024 threads, deterministic reduction of RM pairs.
// (Separate 1-block kernel: cheaper than 3264 device-scope fences -- r7's
// last-block-fused variant cost +120 us from cross-XCD L2 flushes.)
__global__ __launch_bounds__(1024) void k_fin(const double* __restrict__ part,
                                              float* __restrict__ out) {
  const int tid = threadIdx.x;
  double a1 = 0.0, a3 = 0.0;
  for (int r = tid; r < RM; r += 1024) { a1 += part[2 * r]; a3 += part[2 * r + 1]; }
#pragma unroll
  for (int off = 32; off; off >>= 1) {
    a1 += __shfl_down(a1, off);
    a3 += __shfl_down(a3, off);
  }
  __shared__ double s1[16], s3[16];
  const int w = tid >> 6, lane = tid & 63;
  if (lane == 0) { s1[w] = a1; s3[w] = a3; }
  __syncthreads();
  if (tid == 0) {
    double S1 = 0.0, S3 = 0.0;
#pragma unroll
    for (int i = 0; i < 16; ++i) { S1 += s1[i]; S3 += s3[i]; }
    out[0] = (float)(1.0 - sqrt(S1 / S3));   // cp_score
    out[1] = (float)(0.25 * S1 / NELEM);     // k_loss
  }
}

// ---------------------------------------------------------------------------
// Fallback pair (cand in d_out tail): separate merge, then refine (full 5).
__global__ __launch_bounds__(256) void k_merge(const ull* __restrict__ cand,
                                               int* __restrict__ top8) {
  const int lane = threadIdx.x & 63;
  const int row = blockIdx.x * 4 + (threadIdx.x >> 6);
  ull k = lane < NCAND ? cand[(size_t)row * NCAND + lane] : ~0ull;
  k = sort64(k, lane);
  if (lane < NREF) top8[(size_t)row * 8 + lane] = (int)(k & 0xffffffffull);
}

__global__ __launch_bounds__(256) void k_refine_fb(const float* __restrict__ X,
                                                   const float* __restrict__ E,
                                                   const int* __restrict__ top8,
                                                   float* __restrict__ outF,
                                                   double* __restrict__ part) {
  const int lane = threadIdx.x & 63;
  const int row = blockIdx.x * 4 + (threadIdx.x >> 6);
  int ci[NREF];
#pragma unroll
  for (int c = 0; c < NREF; ++c) ci[c] = top8[(size_t)row * 8 + c];
  const float* xr = X + (size_t)row * KD;
  float4 x0 = *(const float4*)(xr + lane * 8);
  float4 x1 = *(const float4*)(xr + lane * 8 + 4);
  refine_x(E, x0, x1, ci, NREF, row, outF, part);
}

// ---------------------------------------------------------------------------
extern "C" void kernel_launch(void* const* d_in, const int* in_sizes, int n_in,
                              void* d_out, int out_size, void* d_ws, size_t ws_size,
                              hipStream_t stream) {
  const float* IP = (const float*)d_in[0];   // (256,51,512) fp32
  const float* EMB = (const float*)d_in[1];  // (2048,512) fp32
  float* out = (float*)d_out;

  // ws layout (16B-aligned): EN | part | top8 | Xh | Eh [| cand]
  char* ws = (char*)d_ws;
  size_t off = 0;
  float* EN = (float*)(ws + off);        off += NE * 4;
  double* part = (double*)(ws + off);    off += (size_t)RM * 2 * 8;  // 209 KB
  int* top8 = (int*)(ws + off);          off += (size_t)RM * 8 * 4;
  unsigned short* Xh = (unsigned short*)(ws + off); off += (size_t)RM * KD * 2;
  unsigned short* Ehs = (unsigned short*)(ws + off); off += (size_t)NE * KD * 2;
  ull* candWs = (ull*)(ws + off);        off += (size_t)RM * NCAND * 8;  // +6.7 MB
  const bool fused = ws_size >= off;     // ~22 MiB for the fused path

  // fallback: cand lives in d_out tail (consumed by k_merge before outF writes)
  ull* cand = fused ? candWs : (ull*)(out + 2);

  hipLaunchKernelGGL(k_prep, dim3(XB + EB + NB), dim3(256), 0, stream,
                     IP, EMB, Xh, Ehs, EN);
  hipLaunchKernelGGL(k_dist_bf16, dim3(GRID_D), dim3(256), 0, stream,
                     Xh, Ehs, EN, cand);
  if (fused) {
    hipLaunchKernelGGL(k_mrf, dim3(NTAIL), dim3(256), 0, stream,
                       IP, EMB, cand, out + 2, part);
  } else {
    hipLaunchKernelGGL(k_merge, dim3(NTAIL), dim3(256), 0, stream, cand, top8);
    hipLaunchKernelGGL(k_refine_fb, dim3(NTAIL), dim3(256), 0, stream,
                       IP, EMB, top8, out + 2, part);
  }
  hipLaunchKernelGGL(k_fin, dim3(1), dim3(1024), 0, stream, part, out);
}